// Round 3
// baseline (355.933 us; speedup 1.0000x reference)
//
#include <hip/hip_runtime.h>
#include <cstddef>

#define TB 256

constexpr int Bb = 8, Ss = 4096, Dd = 1024, Kk = 64, Hh = 8;
constexpr float INV_TEMP = 10.0f;
constexpr float ATTN_SCALE = 0.08838834764831845f; // 1/sqrt(128)

typedef __attribute__((ext_vector_type(8))) short bf16x8;
typedef __attribute__((ext_vector_type(4))) float f32x4;

#define MFMA(a, b, c) __builtin_amdgcn_mfma_f32_16x16x32_bf16(a, b, c, 0, 0, 0)

// ---------------- workspace layout (bytes) ----------------
constexpr size_t OFF_G   = 0;                         // fp32 g[b][s][64]   8 MB
constexpr size_t SZ_G    = (size_t)Bb*Ss*Kk*4;
constexpr size_t OFF_AI  = OFF_G + SZ_G;              // fp32 ai[b][64][1024] 2 MB
constexpr size_t SZ_AKD  = (size_t)Bb*Kk*Dd*4;
constexpr size_t OFF_QKV = OFF_AI + SZ_AKD;           // fp32 6 MB
constexpr size_t OFF_ATT = OFF_QKV + 3*SZ_AKD;        // fp32 2 MB
constexpr size_t OFF_AO  = OFF_ATT + SZ_AKD;          // fp32 2 MB
constexpr size_t OFF_RWH = OFF_AO + SZ_AKD;           // bf16 rw hi 4 MB
constexpr size_t SZ_RW2  = (size_t)Bb*Ss*Kk*2;
constexpr size_t OFF_RWL = OFF_RWH + SZ_RW2;          // bf16 rw lo 4 MB
constexpr size_t OFF_APH = OFF_RWL + SZ_RW2;          // bf16 aopT hi [b][1024][64] 1 MB
constexpr size_t SZ_AP2  = (size_t)Bb*Dd*Kk*2;
constexpr size_t OFF_APL = OFF_APH + SZ_AP2;
constexpr size_t OFF_W1H = OFF_APL + SZ_AP2;          // w1T [64][1024] bf16
constexpr size_t SZ_W1   = (size_t)Kk*Dd*2;
constexpr size_t OFF_W1L = OFF_W1H + SZ_W1;
constexpr size_t OFF_W2H = OFF_W1L + SZ_W1;           // w2T [64][64]
constexpr size_t SZ_W2   = (size_t)Kk*Kk*2;
constexpr size_t OFF_W2L = OFF_W2H + SZ_W2;
constexpr size_t OFF_WQH = OFF_W2L + SZ_W2;           // wqkvT [3072][1024]
constexpr size_t SZ_WQ   = (size_t)3*Dd*Dd*2;
constexpr size_t OFF_WQL = OFF_WQH + SZ_WQ;
constexpr size_t OFF_WOH = OFF_WQL + SZ_WQ;           // woT [1024][1024]
constexpr size_t SZ_WD   = (size_t)Dd*Dd*2;
constexpr size_t OFF_WOL = OFF_WOH + SZ_WD;
constexpr size_t OFF_WPH = OFF_WOL + SZ_WD;           // wpT [1024][1024]
constexpr size_t OFF_WPL = OFF_WPH + SZ_WD;
// total ~= 52.7 MB

// ---------------- scalar helpers ----------------
__device__ inline ushort f2bf(float f) {
    union { float f; uint u; } v; v.f = f;
    return (ushort)((v.u + 0x7fffu + ((v.u >> 16) & 1u)) >> 16);
}
__device__ inline float bf2f(ushort h) {
    union { uint u; float f; } v; v.u = ((uint)h) << 16;
    return v.f;
}
__device__ inline void split2(float f, ushort& h, ushort& l) {
    h = f2bf(f);
    l = f2bf(f - bf2f(h));
}
// 8 floats -> split bf16x8 pair (same rne numerics as round-2)
__device__ inline void cvt8(float4 a, float4 b, bf16x8& h8, bf16x8& l8) {
    float f[8] = {a.x, a.y, a.z, a.w, b.x, b.y, b.z, b.w};
#pragma unroll
    for (int i = 0; i < 8; ++i) {
        ushort hh, ll; split2(f[i], hh, ll);
        h8[i] = (short)hh; l8[i] = (short)ll;
    }
}
// 3-term split-bf16 accumulate (emulated fp32)
__device__ inline f32x4 mm3(bf16x8 ah, bf16x8 al, bf16x8 bh, bf16x8 bl, f32x4 c) {
    c = MFMA(ah, bh, c);
    c = MFMA(ah, bl, c);
    c = MFMA(al, bh, c);
    return c;
}

// ---- swizzled LDS bf16 tile, logical [row][64] (stride 72 ushorts = 144B) ---
__device__ inline void st4(ushort* t, int row, int s0, ushort4 v) {
    char* p = (char*)t + row * 144 + ((((s0 >> 3) ^ ((row >> 2) & 7)) << 4) | ((s0 & 7) << 1));
    *(ushort4*)p = v;
}
__device__ inline void st1(ushort* t, int row, int s, ushort v) {
    char* p = (char*)t + row * 144 + ((((s >> 3) ^ ((row >> 2) & 7)) << 4) | ((s & 7) << 1));
    *(ushort*)p = v;
}
__device__ inline bf16x8 ldfrag(const ushort* t, int row, int sblk) {
    const char* p = (const char*)t + row * 144 + (((sblk ^ ((row >> 2) & 7))) << 4);
    return *(const bf16x8*)p;
}
__device__ inline void natf(ushort* thi, ushort* tlo, int row, int s0, float4 v) {
    ushort h0,h1,h2,h3,l0,l1,l2,l3;
    split2(v.x,h0,l0); split2(v.y,h1,l1); split2(v.z,h2,l2); split2(v.w,h3,l3);
    st4(thi, row, s0, make_ushort4(h0,h1,h2,h3));
    st4(tlo, row, s0, make_ushort4(l0,l1,l2,l3));
}
// transposed split fill from fp32 rows
__device__ inline void trf(ushort* thi, ushort* tlo, int rowbase, int s0,
                           float4 a, float4 b, float4 c, float4 d) {
    float m[4][4] = {{a.x,b.x,c.x,d.x},{a.y,b.y,c.y,d.y},
                     {a.z,b.z,c.z,d.z},{a.w,b.w,c.w,d.w}};
#pragma unroll
    for (int i = 0; i < 4; ++i) {
        ushort h[4], l[4];
#pragma unroll
        for (int j = 0; j < 4; ++j) split2(m[i][j], h[j], l[j]);
        st4(thi, rowbase + i, s0, make_ushort4(h[0],h[1],h[2],h[3]));
        st4(tlo, rowbase + i, s0, make_ushort4(l[0],l[1],l[2],l[3]));
    }
}
// transposed fill from bf16 rows (pure repack, no split)
__device__ inline void trfb(ushort* t, int rowbase, int s0,
                            ushort4 r0, ushort4 r1, ushort4 r2, ushort4 r3) {
    st4(t, rowbase + 0, s0, make_ushort4(r0.x, r1.x, r2.x, r3.x));
    st4(t, rowbase + 1, s0, make_ushort4(r0.y, r1.y, r2.y, r3.y));
    st4(t, rowbase + 2, s0, make_ushort4(r0.z, r1.z, r2.z, r3.z));
    st4(t, rowbase + 3, s0, make_ushort4(r0.w, r1.w, r2.w, r3.w));
}

// ---------------------------------------------------------------------------
// k_zero
// ---------------------------------------------------------------------------
__global__ __launch_bounds__(TB) void k_zero(float* __restrict__ p, int n4) {
    int i = blockIdx.x * TB + threadIdx.x;
    if (i < n4) ((float4*)p)[i] = make_float4(0.f, 0.f, 0.f, 0.f);
}

// ---------------------------------------------------------------------------
// k_prep: transpose + split all weight matrices into bf16 hi/lo, 64x64 tiles
// grid = 16 + 1 + 768 + 256 + 256 = 1297
// ---------------------------------------------------------------------------
__global__ __launch_bounds__(TB) void k_prep(
    const float* __restrict__ w1, const float* __restrict__ w2,
    const float* __restrict__ wq, const float* __restrict__ wo,
    const float* __restrict__ wp,
    ushort* __restrict__ w1h, ushort* __restrict__ w1l,
    ushort* __restrict__ w2h, ushort* __restrict__ w2l,
    ushort* __restrict__ wqh, ushort* __restrict__ wql,
    ushort* __restrict__ woh, ushort* __restrict__ wol,
    ushort* __restrict__ wph, ushort* __restrict__ wpl)
{
    __shared__ float t[64][64];
    const int blk = blockIdx.x, tid = threadIdx.x;
    const float* in; ushort* oh; ushort* ol; int R, IC, r0, c0;
    if (blk < 16)        { in = w1; oh = w1h; ol = w1l; R = 1024; IC = 64;
                           r0 = blk * 64; c0 = 0; }
    else if (blk == 16)  { in = w2; oh = w2h; ol = w2l; R = 64;   IC = 64;
                           r0 = 0; c0 = 0; }
    else if (blk < 785)  { int i = blk - 17; in = wq; oh = wqh; ol = wql;
                           R = 1024; IC = 3072; r0 = (i / 48) * 64; c0 = (i % 48) * 64; }
    else if (blk < 1041) { int i = blk - 785; in = wo; oh = woh; ol = wol;
                           R = 1024; IC = 1024; r0 = (i / 16) * 64; c0 = (i % 16) * 64; }
    else                 { int i = blk - 1041; in = wp; oh = wph; ol = wpl;
                           R = 1024; IC = 1024; r0 = (i / 16) * 64; c0 = (i % 16) * 64; }

    {   // load 64x64 fp32 tile, coalesced
        int r = tid >> 2, cq = (tid & 3) * 16;
        const float* ip = &in[(size_t)(r0 + r) * IC + c0 + cq];
#pragma unroll
        for (int q = 0; q < 4; ++q)
            *(float4*)&t[r][cq + q * 4] = *(const float4*)(ip + q * 4);
    }
    __syncthreads();
    {   // write transposed split rows
        int oc = tid & 63, or0 = (tid >> 6) * 16;
        ushort th[16], tl[16];
#pragma unroll
        for (int i = 0; i < 16; ++i) split2(t[or0 + i][oc], th[i], tl[i]);
        size_t base = (size_t)(c0 + oc) * R + r0 + or0;
#pragma unroll
        for (int q = 0; q < 4; ++q) {
            *(ushort4*)&oh[base + q * 4] = make_ushort4(th[q*4], th[q*4+1], th[q*4+2], th[q*4+3]);
            *(ushort4*)&ol[base + q * 4] = make_ushort4(tl[q*4], tl[q*4+1], tl[q*4+2], tl[q*4+3]);
        }
    }
}

// ---------------------------------------------------------------------------
// k_route1: g[b,s,k] += x[b,s,dh-half] @ w1T (3-term), sync-free, reg-direct
// grid = 8b * 64 stiles(64 tok) * 2 dhalf = 1024
// ---------------------------------------------------------------------------
__global__ __launch_bounds__(TB) void k_route1(
    const float* __restrict__ x, const ushort* __restrict__ w1h,
    const ushort* __restrict__ w1l, float* __restrict__ g)
{
    const int tid = threadIdx.x, lane = tid & 63, wv = tid >> 6;
    const int r15 = lane & 15, gg = lane >> 4;
    const int b = blockIdx.x & 7, st = (blockIdx.x >> 3) & 63, dh = blockIdx.x >> 9;
    const int t0 = st * 64;

    const float* xrow = &x[((size_t)b*Ss + t0 + wv*16 + r15)*Dd + dh*512 + gg*8];

    f32x4 acc[4];
#pragma unroll
    for (int nt = 0; nt < 4; ++nt) acc[nt] = (f32x4)0.f;

    for (int kc = 0; kc < 16; ++kc) {
        float4 xa = *(const float4*)(xrow + kc * 32);
        float4 xb = *(const float4*)(xrow + kc * 32 + 4);
        bf16x8 ah, al; cvt8(xa, xb, ah, al);
#pragma unroll
        for (int nt = 0; nt < 4; ++nt) {
            size_t wi = (size_t)(nt*16 + r15)*Dd + dh*512 + kc*32 + gg*8;
            bf16x8 bh = *(const bf16x8*)&w1h[wi];
            bf16x8 bl = *(const bf16x8*)&w1l[wi];
            acc[nt] = mm3(ah, al, bh, bl, acc[nt]);
        }
    }
#pragma unroll
    for (int nt = 0; nt < 4; ++nt)
#pragma unroll
      for (int j = 0; j < 4; ++j) {
        int row = t0 + wv*16 + gg*4 + j;
        atomicAdd(&g[((size_t)b*Ss + row)*Kk + nt*16 + r15], acc[nt][j]);
      }
}

// ---------------------------------------------------------------------------
// k_route2: rw = softmax((2*energy + relu(g+b1)@w2 + b2)/TEMP) -> split bf16
// grid = 8b * 64 stiles = 512, sync-free, reg-direct
// ---------------------------------------------------------------------------
__global__ __launch_bounds__(TB) void k_route2(
    const float* __restrict__ g, const float* __restrict__ efas,
    const float* __restrict__ w_e, const float* __restrict__ b_e,
    const float* __restrict__ b1, const ushort* __restrict__ w2h,
    const ushort* __restrict__ w2l, const float* __restrict__ b2,
    ushort* __restrict__ rwh, ushort* __restrict__ rwl)
{
    const int tid = threadIdx.x, lane = tid & 63, wv = tid >> 6;
    const int r15 = lane & 15, gg = lane >> 4;
    const int b = blockIdx.x & 7, t0 = (blockIdx.x >> 3) * 64;

    bf16x8 ah[2], al[2];
#pragma unroll
    for (int ks = 0; ks < 2; ++ks) {
        const float* gp = &g[((size_t)b*Ss + t0 + wv*16 + r15)*Kk + ks*32 + gg*8];
        float4 a = *(const float4*)gp, bq = *(const float4*)(gp + 4);
        float4 ba = *(const float4*)&b1[ks*32 + gg*8];
        float4 bb = *(const float4*)&b1[ks*32 + gg*8 + 4];
        a.x = fmaxf(a.x + ba.x, 0.f); a.y = fmaxf(a.y + ba.y, 0.f);
        a.z = fmaxf(a.z + ba.z, 0.f); a.w = fmaxf(a.w + ba.w, 0.f);
        bq.x = fmaxf(bq.x + bb.x, 0.f); bq.y = fmaxf(bq.y + bb.y, 0.f);
        bq.z = fmaxf(bq.z + bb.z, 0.f); bq.w = fmaxf(bq.w + bb.w, 0.f);
        cvt8(a, bq, ah[ks], al[ks]);
    }
    f32x4 acc[4];
#pragma unroll
    for (int nt = 0; nt < 4; ++nt) acc[nt] = (f32x4)0.f;
#pragma unroll
    for (int ks = 0; ks < 2; ++ks)
#pragma unroll
      for (int nt = 0; nt < 4; ++nt) {
        size_t wi = (size_t)(nt*16 + r15)*Kk + ks*32 + gg*8;
        bf16x8 bh = *(const bf16x8*)&w2h[wi];
        bf16x8 bl = *(const bf16x8*)&w2l[wi];
        acc[nt] = mm3(ah[ks], al[ks], bh, bl, acc[nt]);
      }

    float wev[4], bev[4], b2v[4];
#pragma unroll
    for (int nt = 0; nt < 4; ++nt) {
        wev[nt] = w_e[nt*16 + r15]; bev[nt] = b_e[nt*16 + r15]; b2v[nt] = b2[nt*16 + r15];
    }
#pragma unroll
    for (int j = 0; j < 4; ++j) {
        int row = t0 + wv*16 + gg*4 + j;
        float ef = efas[(size_t)b*Ss + row];
        float t[4];
#pragma unroll
        for (int nt = 0; nt < 4; ++nt)
            t[nt] = (acc[nt][j] + b2v[nt] + 2.f*(ef*wev[nt] + bev[nt])) * INV_TEMP;
        float m = fmaxf(fmaxf(t[0], t[1]), fmaxf(t[2], t[3]));
#pragma unroll
        for (int off = 1; off <= 8; off <<= 1) m = fmaxf(m, __shfl_xor(m, off));
        float s = 0.f;
#pragma unroll
        for (int nt = 0; nt < 4; ++nt) { t[nt] = __expf(t[nt] - m); s += t[nt]; }
#pragma unroll
        for (int off = 1; off <= 8; off <<= 1) s += __shfl_xor(s, off);
        float inv = 1.f / s;
#pragma unroll
        for (int nt = 0; nt < 4; ++nt) {
            ushort hh, hl; split2(t[nt] * inv, hh, hl);
            size_t o = ((size_t)b*Ss + row)*Kk + nt*16 + r15;
            rwh[o] = hh; rwl[o] = hl;
        }
    }
}

// ---------------------------------------------------------------------------
// k_anchor: ai[b,k,d] += sum_s rw[s,k]*x[s,d]  (A=rwT bf16, B=xT split fp32)
// grid = 8b * 16dt(64 d) * 8sc(512 s) = 1024
// ---------------------------------------------------------------------------
__global__ __launch_bounds__(TB) void k_anchor(
    const float* __restrict__ x, const ushort* __restrict__ rwh,
    const ushort* __restrict__ rwl, float* __restrict__ ai)
{
    __shared__ __align__(16) ushort rt_h[64*72], rt_l[64*72]; // rwT [k][s]
    __shared__ __align__(16) ushort xt_h[64*72], xt_l[64*72]; // xT  [d][s]
    const int tid = threadIdx.x, lane = tid & 63, wv = tid >> 6;
    const int r15 = lane & 15, gg = lane >> 4;
    const int b = blockIdx.x & 7, dt = (blockIdx.x >> 3) & 15, sc = blockIdx.x >> 7;

    f32x4 acc[4];
#pragma unroll
    for (int mt = 0; mt < 4; ++mt) acc[mt] = (f32x4)0.f;

    const int k0 = (tid & 15) * 4, s0q = (tid >> 4) * 4;
    for (int ss = 0; ss < 8; ++ss) {
        const int sb = sc*512 + ss*64;
        {   // rwT fill (bf16 repack)
            const ushort* rp = &rwh[((size_t)b*Ss + sb + s0q)*Kk + k0];
            trfb(rt_h, k0, s0q, *(const ushort4*)rp, *(const ushort4*)(rp + Kk),
                 *(const ushort4*)(rp + 2*Kk), *(const ushort4*)(rp + 3*Kk));
            const ushort* rp2 = &rwl[((size_t)b*Ss + sb + s0q)*Kk + k0];
            trfb(rt_l, k0, s0q, *(const ushort4*)rp2, *(const ushort4*)(rp2 + Kk),
                 *(const ushort4*)(rp2 + 2*Kk), *(const ushort4*)(rp2 + 3*Kk));
        }
        {   // xT fill (fp32 split)
            const float* xp = &x[((size_t)b*Ss + sb + s0q)*Dd + dt*64 + k0];
            trf(xt_h, xt_l, k0, s0q, *(const float4*)xp, *(const float4*)(xp + Dd),
                *(const float4*)(xp + 2*Dd), *(const float4*)(xp + 3*Dd));
        }
        __syncthreads();
#pragma unroll
        for (int ks = 0; ks < 2; ++ks) {
            bf16x8 bh = ldfrag(xt_h, wv*16 + r15, ks*4 + gg);
            bf16x8 bl = ldfrag(xt_l, wv*16 + r15, ks*4 + gg);
#pragma unroll
            for (int mt = 0; mt < 4; ++mt) {
                bf16x8 ah = ldfrag(rt_h, mt*16 + r15, ks*4 + gg);
                bf16x8 al = ldfrag(rt_l, mt*16 + r15, ks*4 + gg);
                acc[mt] = mm3(ah, al, bh, bl, acc[mt]);
            }
        }
        __syncthreads();
    }
#pragma unroll
    for (int mt = 0; mt < 4; ++mt)
#pragma unroll
      for (int j = 0; j < 4; ++j)
        atomicAdd(&ai[((size_t)b*Kk + mt*16 + gg*4 + j)*Dd + dt*64 + wv*16 + r15],
                  acc[mt][j]);
}

// ---------------------------------------------------------------------------
// k_gemm: C[b,64,N] = A[b,64,1024] @ WT (+bias); reg-direct, sync-free
// TRANSOUT: write aopT split-bf16 [b][1024][64] instead of fp32 C
// grid = 8 * (NDIM/128)
// ---------------------------------------------------------------------------
template <int NDIM, bool HASBIAS, bool TRANSOUT>
__global__ __launch_bounds__(TB) void k_gemm(
    const float* __restrict__ A, const ushort* __restrict__ WH,
    const ushort* __restrict__ WL, const float* __restrict__ bias,
    float* __restrict__ C, ushort* __restrict__ TH, ushort* __restrict__ TL)
{
    const int tid = threadIdx.x, lane = tid & 63, wv = tid >> 6;
    const int r15 = lane & 15, gg = lane >> 4;
    constexpr int NT = NDIM / 128;
    const int b = blockIdx.x / NT, n0 = (blockIdx.x % NT) * 128;

    f32x4 acc[4][2];
#pragma unroll
    for (int mt = 0; mt < 4; ++mt)
#pragma unroll
      for (int nl = 0; nl < 2; ++nl) acc[mt][nl] = (f32x4)0.f;

    for (int kc = 0; kc < 32; ++kc) {
        const int kb = kc * 32;
        bf16x8 ah[4], al[4];
#pragma unroll
        for (int mt = 0; mt < 4; ++mt) {
            const float* ap = &A[((size_t)b*64 + mt*16 + r15)*Dd + kb + gg*8];
            cvt8(*(const float4*)ap, *(const float4*)(ap + 4), ah[mt], al[mt]);
        }
#pragma unroll
        for (int nl = 0; nl < 2; ++nl) {
            size_t wi = (size_t)(n0 + wv*32 + nl*16 + r15)*Dd + kb + gg*8;
            bf16x8 bh = *(const bf16x8*)&WH[wi];
            bf16x8 bl = *(const bf16x8*)&WL[wi];
#pragma unroll
            for (int mt = 0; mt < 4; ++mt)
                acc[mt][nl] = mm3(ah[mt], al[mt], bh, bl, acc[mt][nl]);
        }
    }
#pragma unroll
    for (int nl = 0; nl < 2; ++nl) {
        int col = n0 + wv*32 + nl*16 + r15;
        float bb = HASBIAS ? bias[col] : 0.f;
#pragma unroll
        for (int mt = 0; mt < 4; ++mt)
#pragma unroll
          for (int j = 0; j < 4; ++j) {
            int mrow = mt*16 + gg*4 + j;
            float v = acc[mt][nl][j] + bb;
            if (TRANSOUT) {
                ushort hh, hl; split2(v, hh, hl);
                size_t o = ((size_t)b*Dd + col)*Kk + mrow;
                TH[o] = hh; TL[o] = hl;
            } else {
                C[((size_t)b*64 + mrow)*NDIM + col] = v;
            }
          }
    }
}

// ---------------------------------------------------------------------------
// k_attn (round-2 verbatim): per (b,h) scores + softmax + PV
// grid = 64
// ---------------------------------------------------------------------------
__global__ __launch_bounds__(TB) void k_attn(
    const float* __restrict__ qkv, float* __restrict__ att)
{
    __shared__ __align__(16) ushort qt_hi[64*72],  qt_lo[64*72];
    __shared__ __align__(16) ushort kt_hi[64*72],  kt_lo[64*72];
    __shared__ __align__(16) ushort vt_hi[128*72], vt_lo[128*72];
    const int tid = threadIdx.x, lane = tid & 63, wv = tid >> 6;
    const int b = blockIdx.x >> 3, h = blockIdx.x & 7;
    const int r15 = lane & 15, g = lane >> 4;

    f32x4 accs[4];
#pragma unroll
    for (int nt = 0; nt < 4; ++nt) accs[nt] = (f32x4)0.f;

    for (int ch = 0; ch < 2; ++ch) {
        const int c0 = h*128 + ch*64;
#pragma unroll
        for (int p = 0; p < 4; ++p) {
            int q = tid + p * TB;
            int row = q >> 4, s0 = (q & 15) << 2;
            size_t base = ((size_t)b*64 + row)*3072 + c0 + s0;
            natf(qt_hi, qt_lo, row, s0, *(const float4*)&qkv[base]);
            natf(kt_hi, kt_lo, row, s0, *(const float4*)&qkv[base + 1024]);
        }
        __syncthreads();
#pragma unroll
        for (int ks = 0; ks < 2; ++ks) {
            bf16x8 ah = ldfrag(qt_hi, wv*16 + r15, ks*4 + g);
            bf16x8 al = ldfrag(qt_lo, wv*16 + r15, ks*4 + g);
#pragma unroll
            for (int nt = 0; nt < 4; ++nt) {
                bf16x8 bh = ldfrag(kt_hi, nt*16 + r15, ks*4 + g);
                bf16x8 bl = ldfrag(kt_lo, nt*16 + r15, ks*4 + g);
                accs[nt] = mm3(ah, al, bh, bl, accs[nt]);
            }
        }
        __syncthreads();
    }
    float pr[4][4];
#pragma unroll
    for (int j = 0; j < 4; ++j) {
        float t[4];
#pragma unroll
        for (int nt = 0; nt < 4; ++nt) t[nt] = accs[nt][j] * ATTN_SCALE;
        float m = fmaxf(fmaxf(t[0],t[1]), fmaxf(t[2],t[3]));
#pragma unroll
        for (int off = 1; off <= 8; off <<= 1) m = fmaxf(m, __shfl_xor(m, off));
        float s = 0.f;
#pragma unroll
        for (int nt = 0; nt < 4; ++nt) { t[nt] = __expf(t[nt] - m); s += t[nt]; }
#pragma unroll
        for (int off = 1; off <= 8; off <<= 1) s += __shfl_xor(s, off);
        float inv = 1.f / s;
#pragma unroll
        for (int nt = 0; nt < 4; ++nt) pr[j][nt] = t[nt] * inv;
    }
#pragma unroll
    for (int j = 0; j < 4; ++j)
#pragma unroll
      for (int nt = 0; nt < 4; ++nt) {
        ushort hh, hl; split2(pr[j][nt], hh, hl);
        st1(qt_hi, wv*16 + g*4 + j, nt*16 + r15, hh);
        st1(qt_lo, wv*16 + g*4 + j, nt*16 + r15, hl);
      }
#pragma unroll
    for (int p = 0; p < 2; ++p) {
        int q = tid + p * TB;
        int d0 = (q & 31) << 2, a0 = (q >> 5) << 2;
        const float* base = &qkv[((size_t)b*64 + a0)*3072 + 2048 + h*128 + d0];
        float4 a  = *(const float4*)(base);
        float4 bq = *(const float4*)(base + 3072);
        float4 cq = *(const float4*)(base + 2*3072);
        float4 dq = *(const float4*)(base + 3*3072);
        trf(vt_hi, vt_lo, d0, a0, a, bq, cq, dq);
    }
    __syncthreads();
    f32x4 acc2[8];
#pragma unroll
    for (int nt = 0; nt < 8; ++nt) acc2[nt] = (f32x4)0.f;
#pragma unroll
    for (int ks = 0; ks < 2; ++ks) {
        bf16x8 ah = ldfrag(qt_hi, wv*16 + r15, ks*4 + g);
        bf16x8 al = ldfrag(qt_lo, wv*16 + r15, ks*4 + g);
#pragma unroll
        for (int nt = 0; nt < 8; ++nt) {
            bf16x8 bh = ldfrag(vt_hi, nt*16 + r15, ks*4 + g);
            bf16x8 bl = ldfrag(vt_lo, nt*16 + r15, ks*4 + g);
            acc2[nt] = mm3(ah, al, bh, bl, acc2[nt]);
        }
    }
#pragma unroll
    for (int nt = 0; nt < 8; ++nt)
#pragma unroll
      for (int j = 0; j < 4; ++j)
        att[((size_t)b*64 + wv*16 + g*4 + j)*1024 + h*128 + nt*16 + r15] = acc2[nt][j];
}

// ---------------------------------------------------------------------------
// k_scatter: out = rw @ aop + b_p  (A=rw split rows, B=aopT split rows)
// grid = 8b * 32st(128 tok) * 8dt(128 d) = 2048; sync-free, LDS-free
// ---------------------------------------------------------------------------
__global__ __launch_bounds__(TB) void k_scatter(
    const ushort* __restrict__ rwh, const ushort* __restrict__ rwl,
    const ushort* __restrict__ aph, const ushort* __restrict__ apl,
    const float* __restrict__ b_p, float* __restrict__ out)
{
    const int tid = threadIdx.x, lane = tid & 63, wv = tid >> 6;
    const int r15 = lane & 15, gg = lane >> 4;
    const int b = blockIdx.x & 7, st = (blockIdx.x >> 3) & 31, dt = blockIdx.x >> 8;
    const int t0 = st * 128;

    f32x4 acc[2][8];
#pragma unroll
    for (int mt = 0; mt < 2; ++mt)
#pragma unroll
      for (int nt = 0; nt < 8; ++nt) acc[mt][nt] = (f32x4)0.f;

#pragma unroll
    for (int ks = 0; ks < 2; ++ks) {
        bf16x8 ah[2], al[2];
#pragma unroll
        for (int mt = 0; mt < 2; ++mt) {
            size_t ri = ((size_t)b*Ss + t0 + wv*32 + mt*16 + r15)*Kk + ks*32 + gg*8;
            ah[mt] = *(const bf16x8*)&rwh[ri];
            al[mt] = *(const bf16x8*)&rwl[ri];
        }
#pragma unroll
        for (int nt = 0; nt < 8; ++nt) {
            size_t bi = ((size_t)b*Dd + dt*128 + nt*16 + r15)*Kk + ks*32 + gg*8;
            bf16x8 bh = *(const bf16x8*)&aph[bi];
            bf16x8 bl = *(const bf16x8*)&apl[bi];
#pragma unroll
            for (int mt = 0; mt < 2; ++mt)
                acc[mt][nt] = mm3(ah[mt], al[mt], bh, bl, acc[mt][nt]);
        }
    }
#pragma unroll
    for (int nt = 0; nt < 8; ++nt) {
        float bp = b_p[dt*128 + nt*16 + r15];
#pragma unroll
        for (int mt = 0; mt < 2; ++mt)
#pragma unroll
          for (int j = 0; j < 4; ++j)
            out[((size_t)b*Ss + t0 + wv*32 + mt*16 + gg*4 + j)*Dd + dt*128 + nt*16 + r15]
                = acc[mt][nt][j] + bp;
    }
}

extern "C" void kernel_launch(void* const* d_in, const int* in_sizes, int n_in,
                              void* d_out, int out_size, void* d_ws, size_t ws_size,
                              hipStream_t stream)
{
    const float* x     = (const float*)d_in[0];
    const float* efas  = (const float*)d_in[1];
    const float* w_e   = (const float*)d_in[2];
    const float* b_e   = (const float*)d_in[3];
    const float* w1    = (const float*)d_in[4];
    const float* b1    = (const float*)d_in[5];
    const float* w2    = (const float*)d_in[6];
    const float* b2    = (const float*)d_in[7];
    const float* w_qkv = (const float*)d_in[8];
    const float* b_qkv = (const float*)d_in[9];
    const float* w_o   = (const float*)d_in[10];
    const float* b_o   = (const float*)d_in[11];
    const float* w_p   = (const float*)d_in[12];
    const float* b_p   = (const float*)d_in[13];
    float* out = (float*)d_out;
    char* ws = (char*)d_ws;

    float*  g   = (float*)(ws + OFF_G);
    float*  ai  = (float*)(ws + OFF_AI);
    float*  qkv = (float*)(ws + OFF_QKV);
    float*  att = (float*)(ws + OFF_ATT);
    float*  ao  = (float*)(ws + OFF_AO);
    ushort* rwh = (ushort*)(ws + OFF_RWH);
    ushort* rwl = (ushort*)(ws + OFF_RWL);
    ushort* aph = (ushort*)(ws + OFF_APH);
    ushort* apl = (ushort*)(ws + OFF_APL);
    ushort* w1h = (ushort*)(ws + OFF_W1H);
    ushort* w1l = (ushort*)(ws + OFF_W1L);
    ushort* w2h = (ushort*)(ws + OFF_W2H);
    ushort* w2l = (ushort*)(ws + OFF_W2L);
    ushort* wqh = (ushort*)(ws + OFF_WQH);
    ushort* wql = (ushort*)(ws + OFF_WQL);
    ushort* woh = (ushort*)(ws + OFF_WOH);
    ushort* wol = (ushort*)(ws + OFF_WOL);
    ushort* wph = (ushort*)(ws + OFF_WPH);
    ushort* wpl = (ushort*)(ws + OFF_WPL);

    hipLaunchKernelGGL(k_prep, dim3(1297), dim3(TB), 0, stream,
                       w1, w2, w_qkv, w_o, w_p,
                       w1h, w1l, w2h, w2l, wqh, wql, woh, wol, wph, wpl);
    hipLaunchKernelGGL(k_zero, dim3(2560), dim3(TB), 0, stream,
                       g, (int)((SZ_G + SZ_AKD) / 16));
    hipLaunchKernelGGL(k_route1, dim3(1024), dim3(TB), 0, stream, x, w1h, w1l, g);
    hipLaunchKernelGGL(k_route2, dim3(512), dim3(TB), 0, stream,
                       g, efas, w_e, b_e, b1, w2h, w2l, b2, rwh, rwl);
    hipLaunchKernelGGL(k_anchor, dim3(1024), dim3(TB), 0, stream, x, rwh, rwl, ai);
    hipLaunchKernelGGL((k_gemm<3072, true, false>), dim3(192), dim3(TB), 0, stream,
                       ai, wqh, wql, b_qkv, qkv, (ushort*)nullptr, (ushort*)nullptr);
    hipLaunchKernelGGL(k_attn, dim3(64), dim3(TB), 0, stream, qkv, att);
    hipLaunchKernelGGL((k_gemm<1024, true, false>), dim3(64), dim3(TB), 0, stream,
                       att, woh, wol, b_o, ao, (ushort*)nullptr, (ushort*)nullptr);
    hipLaunchKernelGGL((k_gemm<1024, false, true>), dim3(64), dim3(TB), 0, stream,
                       ao, wph, wpl, (const float*)nullptr, (float*)nullptr, aph, apl);
    hipLaunchKernelGGL(k_scatter, dim3(2048), dim3(TB), 0, stream,
                       rwh, rwl, aph, apl, b_p, out);
}